// Round 3
// baseline (251.511 us; speedup 1.0000x reference)
//
#include <hip/hip_runtime.h>
#include <hip/hip_bf16.h>

// Conv2d: in (32,128,56,56) f32, w (256,128,3,3) f32, bias(256) f32
// out (32,256,56,56) f32.  Implicit-GEMM, bf16 MFMA 16x16x32.
// R3: A staged ONCE per block as a 10x18x128 halo in LDS (1 barrier/block);
//     B fragments loaded straight to registers from a lane-ordered w3 tensor
//     (L2-resident), prefetched one rs-stage ahead.
//
// ws:  [0, 1MB)           : w3  bf16 [rs9][kot2][nw2][cc2][ks2][nf4][lane64][8]
//      [1MB, 1MB+30.4MB)  : in_pad bf16 [32][58][64][128] (zero-padded NHWC)

typedef __bf16 bf16x8 __attribute__((ext_vector_type(8)));
typedef float f32x4 __attribute__((ext_vector_type(4)));

#define N_IMG 32
#define C_IN 128
#define HW 56
#define K_OUT 256
#define YPAD 58
#define XPAD 64
#define IN_PAD_OFF 1048576ul

__device__ __forceinline__ void gl_lds16(const __bf16* g, __bf16* l) {
    __builtin_amdgcn_global_load_lds(
        (const __attribute__((address_space(1))) unsigned int*)(const void*)g,
        (__attribute__((address_space(3))) unsigned int*)(void*)l,
        16, 0, 0);
}

// ---- pre-pass: weight OIHW f32 -> w3 lane-ordered bf16 (16B stores) ----------
// w3 elem index = ((((((rs*2+kot)*2+nw)*2+cc)*2+ks)*4+nf)*64 + lane)*8 + j
// maps to ko = kot*128+nw*64+nf*16+(lane&15), c = cc*64+ks*32+(lane>>4)*8+j
__global__ void prep_weight(const float* __restrict__ wt, __bf16* __restrict__ w3) {
    int idx = blockIdx.x * 256 + threadIdx.x;      // 36864
    if (idx >= 9 * 2 * 2 * 2 * 2 * 4 * 64) return;
    int lane = idx & 63;
    int t = idx >> 6;
    int nf = t & 3;  t >>= 2;
    int ks = t & 1;  t >>= 1;
    int cc = t & 1;  t >>= 1;
    int nw = t & 1;  t >>= 1;
    int kot = t & 1; t >>= 1;
    int rs = t;                                    // 0..8
    int ko = kot * 128 + nw * 64 + nf * 16 + (lane & 15);
    int c0 = cc * 64 + ks * 32 + (lane >> 4) * 8;
    const float* src = wt + ((size_t)ko * C_IN + c0) * 9 + rs;
    bf16x8 v;
#pragma unroll
    for (int j = 0; j < 8; ++j) v[j] = (__bf16)src[j * 9];
    *(bf16x8*)(w3 + (size_t)idx * 8) = v;
}

// ------------- pre-pass: input NCHW f32 -> padded NHWC bf16 (unchanged) -------
__global__ void prep_input(const float* __restrict__ in, __bf16* __restrict__ in_pad) {
    int bid = blockIdx.x;                 // 32*58 = 1856
    int y = bid % YPAD;
    int n = bid / YPAD;
    int h = y - 1;
    bool interior = (h >= 0 && h < HW);
    __shared__ float tile[HW * 130];      // [w][c], pitch 130
    int t = threadIdx.x;
    if (interior) {
        const float* src = in + (size_t)n * C_IN * (HW * HW) + (size_t)h * HW;
#pragma unroll 1
        for (int idx = t; idx < C_IN * 14; idx += 256) {   // float4 reads
            int c = idx / 14, g = idx % 14;
            f32x4 v = *(const f32x4*)(src + (size_t)c * (HW * HW) + g * 4);
            int w = g * 4;
            tile[(w + 0) * 130 + c] = v.x;
            tile[(w + 1) * 130 + c] = v.y;
            tile[(w + 2) * 130 + c] = v.z;
            tile[(w + 3) * 130 + c] = v.w;
        }
    }
    __syncthreads();
    __bf16* dst = in_pad + (size_t)(n * YPAD + y) * XPAD * C_IN;
#pragma unroll 1
    for (int idx = t; idx < XPAD * 16; idx += 256) {       // 16B stores
        int x = idx >> 4, cg = idx & 15;
        bf16x8 v8;
        if (interior && x >= 1 && x <= HW) {
            const float* tp = tile + (x - 1) * 130 + cg * 8;
#pragma unroll
            for (int k = 0; k < 8; ++k) v8[k] = (__bf16)tp[k];
        } else {
#pragma unroll
            for (int k = 0; k < 8; ++k) v8[k] = (__bf16)0.f;
        }
        *(bf16x8*)(dst + x * C_IN + cg * 8) = v8;
    }
}

// ---------------- main kernel: halo-LDS implicit-GEMM conv ---------------------
// block 256 thr = 4 waves (2 mw x 2 nw), tile 128M (8h x 16w) x 128N (ko).
// LDS: single 10x18x128 bf16 halo (45 KB), staged once, ONE barrier.
// 18 compute stages (9 rs x 2 c64); B frags to regs, prefetch 1 stage ahead.
// LDS layout: [y(10)][x(18)][slot(16)x8elem], chunk cs stored at slot cs^(x&7).
__global__ __launch_bounds__(256, 3) void conv_mfma(
        const __bf16* __restrict__ in_pad,   // [32][58][64][128]
        const __bf16* __restrict__ w3,
        const float* __restrict__ bias,
        float* __restrict__ out)             // [32][256][56][56]
{
    __shared__ __align__(16) __bf16 sA[10 * 18 * 128];   // 46080 B

    int bid  = blockIdx.x;
    int kot  = bid & 1;
    int wt_  = (bid >> 1) & 3;
    int rest = bid >> 3;
    int ht   = rest % 7;
    int n    = rest / 7;

    int h0  = ht * 8;
    int w0  = (wt_ == 3) ? 40 : wt_ * 16;    // last w-tile overlaps: no masks
    int ko0 = kot * 128;

    int tid  = threadIdx.x;
    int lane = tid & 63;
    int wave = tid >> 6;
    int mw   = wave & 1;
    int nw   = wave >> 1;
    int l15  = lane & 15;
    int quad = lane >> 4;

    // halo covers padded rows h0..h0+9, padded cols w0..w0+17
    const __bf16* aG = in_pad + (((size_t)n * YPAD + h0) * XPAD + w0) * C_IN;

    // ---- stage halo: 2880 16B-chunks, chunk = (y*18+x)*16 + cs ----
#pragma unroll
    for (int q = 0; q < 12; ++q) {
        int chunk = q * 256 + tid;
        if (chunk < 2880) {
            int cs = chunk & 15;
            int xy = chunk >> 4;
            int x  = xy % 18;
            int y  = xy / 18;
            gl_lds16(aG + (y * XPAD + x) * C_IN + ((cs ^ (x & 7)) * 8),
                     sA + (size_t)(q * 256 + wave * 64) * 8);
        }
    }

    // ---- B fragment base (contiguous 1KB per frag per wave) ----
    const __bf16* bW = w3 + (size_t)(kot * 2 + nw) * 8192 + lane * 8;

    bf16x8 b[2][8];
#pragma unroll
    for (int ks = 0; ks < 2; ++ks)
#pragma unroll
        for (int nf = 0; nf < 4; ++nf)
            b[0][ks * 4 + nf] = *(const bf16x8*)(bW + ks * 2048 + nf * 512);

    __syncthreads();    // halo staged (vmcnt(0) drained here, once per block)

    f32x4 acc[4][4] = {};

#pragma unroll
    for (int st = 0; st < 18; ++st) {
        int cc = st / 9, rs = st % 9;
        if (st < 17) {
            int ncc = (st + 1) / 9, nrs = (st + 1) % 9;
#pragma unroll
            for (int ks = 0; ks < 2; ++ks)
#pragma unroll
                for (int nf = 0; nf < 4; ++nf)
                    b[(st + 1) & 1][ks * 4 + nf] = *(const bf16x8*)
                        (bW + nrs * 32768 + ncc * 4096 + ks * 2048 + nf * 512);
        }
        int r = rs / 3, s = rs % 3;
        int x = l15 + s;
        int x7 = x & 7;
#pragma unroll
        for (int ks = 0; ks < 2; ++ks) {
            int slot = (cc * 8 + ks * 4 + quad) ^ x7;
            bf16x8 a[4];
#pragma unroll
            for (int mf = 0; mf < 4; ++mf) {
                int y = mw * 4 + mf + r;
                a[mf] = *(const bf16x8*)(sA + (y * 18 + x) * 128 + slot * 8);
            }
#pragma unroll
            for (int mf = 0; mf < 4; ++mf)
#pragma unroll
                for (int nf = 0; nf < 4; ++nf)
                    acc[mf][nf] = __builtin_amdgcn_mfma_f32_16x16x32_bf16(
                        a[mf], b[st & 1][ks * 4 + nf], acc[mf][nf], 0, 0, 0);
        }
    }

    // epilogue: D[row=quad*4+reg][col=l15]; row -> w, col -> ko-within-16
#pragma unroll
    for (int nf = 0; nf < 4; ++nf) {
        int ko = ko0 + nw * 64 + nf * 16 + l15;
        float bs = bias[ko];
        float* outb = out + (size_t)(n * K_OUT + ko) * (HW * HW)
                          + (size_t)(h0 + mw * 4) * HW + w0 + quad * 4;
#pragma unroll
        for (int mf = 0; mf < 4; ++mf) {
            f32x4 v = acc[mf][nf];
            v = v + bs;
            *(f32x4*)(outb + mf * HW) = v;
        }
    }
}

// ---------------- fallback: naive direct conv (only if ws too small) -----------
__global__ void conv_naive(const float* __restrict__ in, const float* __restrict__ wt,
                           const float* __restrict__ bias, float* __restrict__ out) {
    size_t idx = (size_t)blockIdx.x * 256 + threadIdx.x;
    size_t total = (size_t)N_IMG * K_OUT * HW * HW;
    if (idx >= total) return;
    int w  = idx % HW;
    int h  = (idx / HW) % HW;
    int ko = (idx / (HW * HW)) % K_OUT;
    int n  = idx / ((size_t)HW * HW * K_OUT);
    float acc = bias[ko];
    for (int c = 0; c < C_IN; ++c)
        for (int r = 0; r < 3; ++r) {
            int y = h + r - 1;
            if (y < 0 || y >= HW) continue;
            for (int s = 0; s < 3; ++s) {
                int x = w + s - 1;
                if (x < 0 || x >= HW) continue;
                acc += in[((size_t)(n * C_IN + c) * HW + y) * HW + x]
                     * wt[((size_t)ko * C_IN + c) * 9 + r * 3 + s];
            }
        }
    out[idx] = acc;
}

extern "C" void kernel_launch(void* const* d_in, const int* in_sizes, int n_in,
                              void* d_out, int out_size, void* d_ws, size_t ws_size,
                              hipStream_t stream) {
    const float* in   = (const float*)d_in[0];
    const float* wt   = (const float*)d_in[1];
    const float* bias = (const float*)d_in[2];
    float* out = (float*)d_out;

    size_t need = IN_PAD_OFF + (size_t)N_IMG * YPAD * XPAD * C_IN * 2;
    if (ws_size >= need) {
        __bf16* w3     = (__bf16*)d_ws;
        __bf16* in_pad = (__bf16*)((char*)d_ws + IN_PAD_OFF);
        prep_weight<<<(9 * 2 * 2 * 2 * 2 * 4 * 64 + 255) / 256, 256, 0, stream>>>(wt, w3);
        prep_input<<<N_IMG * YPAD, 256, 0, stream>>>(in, in_pad);
        conv_mfma<<<N_IMG * 7 * 4 * 2, 256, 0, stream>>>(in_pad, w3, bias, out);
    } else {
        size_t total = (size_t)N_IMG * K_OUT * HW * HW;
        conv_naive<<<(unsigned)((total + 255) / 256), 256, 0, stream>>>(in, wt, bias, out);
    }
}